// Round 2
// baseline (852.586 us; speedup 1.0000x reference)
//
#include <hip/hip_runtime.h>
#include <stdint.h>

// ---------------------------------------------------------------------------
// InfoNCE loss (B=32, C=512, G=16, P=5, neg=16, skip=1), fp32 inputs.
// Reproduces jax.random.randint(jax.random.key(1000+k), (N*16,), 0, N)
// bit-exactly via Threefry-2x32.
// JAX_PARTITIONABLE=1 assumes jax_threefry_partitionable default-on (JAX>=0.4.30).
// ---------------------------------------------------------------------------

#define JAX_PARTITIONABLE 1

__host__ __device__ inline uint32_t rotl32(uint32_t x, int d) {
  return (x << d) | (x >> (32 - d));
}

__host__ __device__ inline void tf2x32(uint32_t k0, uint32_t k1,
                                       uint32_t x0, uint32_t x1,
                                       uint32_t& o0, uint32_t& o1) {
  uint32_t ks0 = k0, ks1 = k1, ks2 = 0x1BD11BDAu ^ k0 ^ k1;
  x0 += ks0; x1 += ks1;
#define TF_R(r) { x0 += x1; x1 = rotl32(x1, (r)); x1 ^= x0; }
  TF_R(13) TF_R(15) TF_R(26) TF_R(6)
  x0 += ks1; x1 += ks2 + 1u;
  TF_R(17) TF_R(29) TF_R(16) TF_R(24)
  x0 += ks2; x1 += ks0 + 2u;
  TF_R(13) TF_R(15) TF_R(26) TF_R(6)
  x0 += ks0; x1 += ks1 + 3u;
  TF_R(17) TF_R(29) TF_R(16) TF_R(24)
  x0 += ks1; x1 += ks2 + 4u;
  TF_R(13) TF_R(15) TF_R(26) TF_R(6)
  x0 += ks2; x1 += ks0 + 5u;
#undef TF_R
  o0 = x0; o1 = x1;
}

// ---------------------------------------------------------------------------
// perm: dst[((g*16+j)*32+b)*512 + cc] = src[b*131072 + cc*256 + g*16 + j]
// grid = 16*32 blocks (g,b); both read and write 64B-coalesced via LDS tile.
// ---------------------------------------------------------------------------
__global__ __launch_bounds__(256) void perm_kernel(const float* __restrict__ src,
                                                   float* __restrict__ dst) {
  int g = blockIdx.x >> 5;
  int b = blockIdx.x & 31;
  __shared__ float tile[512][17];
  int t = threadIdx.x;
#pragma unroll 4
  for (int it = 0; it < 32; ++it) {
    int e = it * 256 + t;
    int cc = e >> 4, j = e & 15;
    tile[cc][j] = src[b * 131072 + cc * 256 + g * 16 + j];
  }
  __syncthreads();
#pragma unroll 4
  for (int it = 0; it < 32; ++it) {
    int e = it * 256 + t;
    int cc = e & 511, jj = e >> 9;
    dst[((g * 16 + jj) * 32 + b) * 512 + cc] = tile[cc][jj];
  }
}

// ---------------------------------------------------------------------------
// ztwk GEMM: Cout[r, o] = sum_c A[r, c] * Wk[o, c]
// A = zperm + koff*512*512 (rows contiguous), Wk row-major (512,512).
// BM=BN=64, BK=32, 256 threads, 4x4 microtile.
// ---------------------------------------------------------------------------
#define BM 64
#define BN 64
#define BK 32

__global__ __launch_bounds__(256) void gemm_ztwk(const float* __restrict__ A,
                                                 const float* __restrict__ Wk,
                                                 float* __restrict__ Cout, int M) {
  __shared__ float Xs[BM][BK + 4];  // [m][kk]
  __shared__ float Ws[BK][BN + 4];  // [kk][n]
  int tid = threadIdx.x;
  int r0 = blockIdx.x * BM, n0 = blockIdx.y * BN;
  int tm = tid >> 4, tn = tid & 15;
  float acc[4][4] = {};
  for (int c0 = 0; c0 < 512; c0 += BK) {
#pragma unroll
    for (int t = 0; t < 2; ++t) {
      int f = tid + t * 256;        // float4 index in 64x32 tile
      int m = f >> 3, k4 = f & 7;
      float4 v = *reinterpret_cast<const float4*>(&A[(size_t)(r0 + m) * 512 + c0 + k4 * 4]);
      Xs[m][k4 * 4 + 0] = v.x; Xs[m][k4 * 4 + 1] = v.y;
      Xs[m][k4 * 4 + 2] = v.z; Xs[m][k4 * 4 + 3] = v.w;
    }
#pragma unroll
    for (int t = 0; t < 2; ++t) {
      int f = tid + t * 256;
      int n = f >> 3, k4 = f & 7;
      float4 v = *reinterpret_cast<const float4*>(&Wk[(size_t)(n0 + n) * 512 + c0 + k4 * 4]);
      Ws[k4 * 4 + 0][n] = v.x; Ws[k4 * 4 + 1][n] = v.y;
      Ws[k4 * 4 + 2][n] = v.z; Ws[k4 * 4 + 3][n] = v.w;
    }
    __syncthreads();
#pragma unroll
    for (int kk = 0; kk < BK; ++kk) {
      float xa[4], wb[4];
#pragma unroll
      for (int a = 0; a < 4; ++a) xa[a] = Xs[tm * 4 + a][kk];
#pragma unroll
      for (int b = 0; b < 4; ++b) wb[b] = Ws[kk][tn * 4 + b];
#pragma unroll
      for (int a = 0; a < 4; ++a)
#pragma unroll
        for (int b = 0; b < 4; ++b) acc[a][b] += xa[a] * wb[b];
    }
    __syncthreads();
  }
#pragma unroll
  for (int a = 0; a < 4; ++a) {
    float4 v = make_float4(acc[a][0], acc[a][1], acc[a][2], acc[a][3]);
    *reinterpret_cast<float4*>(&Cout[(size_t)(r0 + tm * 4 + a) * 512 + n0 + tn * 4]) = v;
  }
}

// ---------------------------------------------------------------------------
// idx kernel: reproduce jax.random.randint indices.
// ---------------------------------------------------------------------------
__global__ __launch_bounds__(256) void idx_kernel(int* __restrict__ idx, int size,
                                                  uint32_t span, uint32_t mult,
                                                  uint32_t k1a, uint32_t k1b,
                                                  uint32_t k2a, uint32_t k2b) {
  int m = blockIdx.x * 256 + threadIdx.x;
  if (m >= size) return;
#if JAX_PARTITIONABLE
  uint32_t h0, h1, l0, l1;
  tf2x32(k1a, k1b, 0u, (uint32_t)m, h0, h1);
  tf2x32(k2a, k2b, 0u, (uint32_t)m, l0, l1);
  uint32_t hi = h0 ^ h1, lo = l0 ^ l1;
#else
  int half = size >> 1;
  int mm = (m < half) ? m : (m - half);
  uint32_t h0, h1, l0, l1;
  tf2x32(k1a, k1b, (uint32_t)mm, (uint32_t)(mm + half), h0, h1);
  tf2x32(k2a, k2b, (uint32_t)mm, (uint32_t)(mm + half), l0, l1);
  uint32_t hi = (m < half) ? h0 : h1;
  uint32_t lo = (m < half) ? l0 : l1;
#endif
  uint32_t off = ((hi % span) * mult + (lo % span)) % span;
  idx[m] = (int)off;
}

// ---------------------------------------------------------------------------
// loss kernel: one wave per row r. 17 dots of length 512, softmax, log,
// scaled atomicAdd into out[0].
// ---------------------------------------------------------------------------
__device__ inline float wave_sum(float v) {
#pragma unroll
  for (int o = 32; o > 0; o >>= 1) v += __shfl_xor(v, o, 64);
  return v;
}

__global__ __launch_bounds__(256) void loss_kernel(const float* __restrict__ ztwk,
                                                   const float* __restrict__ cperm,
                                                   const int* __restrict__ idx,
                                                   float* __restrict__ out,
                                                   int M, float scale) {
  int wave = threadIdx.x >> 6, lane = threadIdx.x & 63;
  int r = blockIdx.x * 4 + wave;
  if (r >= M) return;

  float creg[8];
  {
    const float4* c4 = reinterpret_cast<const float4*>(&cperm[(size_t)r * 512 + lane * 8]);
    float4 v0 = c4[0], v1 = c4[1];
    creg[0] = v0.x; creg[1] = v0.y; creg[2] = v0.z; creg[3] = v0.w;
    creg[4] = v1.x; creg[5] = v1.y; creg[6] = v1.z; creg[7] = v1.w;
  }
  float logits[17];
  {
    const float4* z4 = reinterpret_cast<const float4*>(&ztwk[(size_t)r * 512 + lane * 8]);
    float4 a = z4[0], b = z4[1];
    float s = creg[0] * a.x + creg[1] * a.y + creg[2] * a.z + creg[3] * a.w +
              creg[4] * b.x + creg[5] * b.y + creg[6] * b.z + creg[7] * b.w;
    logits[0] = wave_sum(s);
  }
#pragma unroll 4
  for (int n = 0; n < 16; ++n) {
    int rn = idx[r * 16 + n];
    const float4* z4 = reinterpret_cast<const float4*>(&ztwk[(size_t)rn * 512 + lane * 8]);
    float4 a = z4[0], b = z4[1];
    float s = creg[0] * a.x + creg[1] * a.y + creg[2] * a.z + creg[3] * a.w +
              creg[4] * b.x + creg[5] * b.y + creg[6] * b.z + creg[7] * b.w;
    logits[1 + n] = wave_sum(s);
  }
  if (lane == 0) {
    float mx = logits[0];
#pragma unroll
    for (int i = 1; i < 17; ++i) mx = fmaxf(mx, logits[i]);
    float ssum = 0.0f;
#pragma unroll
    for (int i = 0; i < 17; ++i) ssum += __expf(logits[i] - mx);
    float p0 = __expf(logits[0] - mx) / ssum;
    atomicAdd(out, -logf(p0 + 1e-11f) * scale);
  }
}

__global__ void zero_out(float* o) {
  if (threadIdx.x == 0) o[0] = 0.0f;
}

// ---------------------------------------------------------------------------
extern "C" void kernel_launch(void* const* d_in, const int* in_sizes, int n_in,
                              void* d_out, int out_size, void* d_ws, size_t ws_size,
                              hipStream_t stream) {
  const float* z = (const float*)d_in[0];
  const float* c = (const float*)d_in[1];
  const float* W = (const float*)d_in[2];
  // neg_samples=16, skip_step=1 fixed by setup_inputs (d_in[3], d_in[4]).
  float* out = (float*)d_out;

  float* zperm = (float*)d_ws;           // 8192*512 f32 = 16 MB
  float* cperm = zperm + 8192 * 512;     // 16 MB
  float* ztwk  = cperm + 8192 * 512;     // up to 7168*512 f32 = 14 MB
  int*   idx   = (int*)(ztwk + 7168 * 512);  // up to 7168*16 int32

  zero_out<<<dim3(1), dim3(64), 0, stream>>>(out);
  perm_kernel<<<dim3(512), dim3(256), 0, stream>>>(z, zperm);
  perm_kernel<<<dim3(512), dim3(256), 0, stream>>>(c, cperm);

  for (int k = 1; k <= 5; ++k) {
    int koff = k + 1;          // k + skip_step
    int Gp = 16 - koff;
    int M = Gp * 512;          // Gp * G * B
    uint32_t span = (uint32_t)M;
    uint32_t mult = (uint32_t)((1ull << 32) % (uint64_t)span);
    uint32_t key0 = 0u, key1 = (uint32_t)(1000 + k);
    uint32_t k1a, k1b, k2a, k2b;
#if JAX_PARTITIONABLE
    tf2x32(key0, key1, 0u, 0u, k1a, k1b);   // split -> key[0]
    tf2x32(key0, key1, 0u, 1u, k2a, k2b);   // split -> key[1]
#else
    uint32_t a0, b0, a1, b1;
    tf2x32(key0, key1, 0u, 2u, a0, b0);
    tf2x32(key0, key1, 1u, 3u, a1, b1);
    k1a = a0; k1b = a1; k2a = b0; k2b = b1;
#endif
    int size = M * 16;

    gemm_ztwk<<<dim3(M / 64, 8), dim3(256), 0, stream>>>(
        zperm + (size_t)koff * 512 * 512, W + (size_t)(k - 1) * 512 * 512, ztwk, M);
    idx_kernel<<<dim3((size + 255) / 256), dim3(256), 0, stream>>>(
        idx, size, span, mult, k1a, k1b, k2a, k2b);
    float scale = 1.0f / ((float)M * 5.0f);
    loss_kernel<<<dim3(M / 4), dim3(256), 0, stream>>>(ztwk, cperm, idx, out, M, scale);
  }
}

// Round 3
// 204.139 us; speedup vs baseline: 4.1765x; 4.1765x over previous
//
#include <hip/hip_runtime.h>
#include <stdint.h>

// ---------------------------------------------------------------------------
// InfoNCE loss (B=32, C=512, G=16, P=5, neg=16, skip=1), fp32 inputs.
// Round 3: bf16 MFMA GEMM + fused latency-optimized loss gather.
// Threefry-2x32 (partitionable) reproduces jax.random.randint bit-exactly
// (verified round 2: absmax 0.0).
// ---------------------------------------------------------------------------

typedef __attribute__((ext_vector_type(8))) short bf16x8;
typedef __attribute__((ext_vector_type(4))) float f32x4;

__host__ __device__ inline uint32_t rotl32(uint32_t x, int d) {
  return (x << d) | (x >> (32 - d));
}

__host__ __device__ inline void tf2x32(uint32_t k0, uint32_t k1,
                                       uint32_t x0, uint32_t x1,
                                       uint32_t& o0, uint32_t& o1) {
  uint32_t ks0 = k0, ks1 = k1, ks2 = 0x1BD11BDAu ^ k0 ^ k1;
  x0 += ks0; x1 += ks1;
#define TF_R(r) { x0 += x1; x1 = rotl32(x1, (r)); x1 ^= x0; }
  TF_R(13) TF_R(15) TF_R(26) TF_R(6)
  x0 += ks1; x1 += ks2 + 1u;
  TF_R(17) TF_R(29) TF_R(16) TF_R(24)
  x0 += ks2; x1 += ks0 + 2u;
  TF_R(13) TF_R(15) TF_R(26) TF_R(6)
  x0 += ks0; x1 += ks1 + 3u;
  TF_R(17) TF_R(29) TF_R(16) TF_R(24)
  x0 += ks1; x1 += ks2 + 4u;
  TF_R(13) TF_R(15) TF_R(26) TF_R(6)
  x0 += ks2; x1 += ks0 + 5u;
#undef TF_R
  o0 = x0; o1 = x1;
}

__device__ inline ushort f2bf(float f) {
  uint32_t u = __builtin_bit_cast(uint32_t, f);
  u += 0x7FFFu + ((u >> 16) & 1u);
  return (ushort)(u >> 16);
}

// ---------------------------------------------------------------------------
// perm -> bf16: dst[((g*16+j)*32+b)*512 + cc] = bf16(src[b*131072+cc*256+g*16+j])
// ---------------------------------------------------------------------------
__global__ __launch_bounds__(256) void perm_bf16(const float* __restrict__ src,
                                                 ushort* __restrict__ dst) {
  int g = blockIdx.x >> 5;
  int b = blockIdx.x & 31;
  __shared__ ushort tile[512][17];
  int t = threadIdx.x;
#pragma unroll 4
  for (int it = 0; it < 32; ++it) {
    int e = it * 256 + t;
    int cc = e >> 4, j = e & 15;
    tile[cc][j] = f2bf(src[b * 131072 + cc * 256 + g * 16 + j]);
  }
  __syncthreads();
#pragma unroll 4
  for (int it = 0; it < 32; ++it) {
    int e = it * 256 + t;
    int cc = e & 511, jj = e >> 9;
    dst[(size_t)((g * 16 + jj) * 32 + b) * 512 + cc] = tile[cc][jj];
  }
}

// W (5,512,512) fp32 -> bf16
__global__ __launch_bounds__(256) void conv_w(const float4* __restrict__ W,
                                              ushort* __restrict__ Wb) {
  int gid = blockIdx.x * 256 + threadIdx.x;
  if (gid >= 327680) return;
  float4 v = W[gid];
  ushort4 o;
  o.x = f2bf(v.x); o.y = f2bf(v.y); o.z = f2bf(v.z); o.w = f2bf(v.w);
  *reinterpret_cast<ushort4*>(&Wb[(size_t)gid * 4]) = o;
}

// ---------------------------------------------------------------------------
// Batched bf16 MFMA GEMM over all 5 steps.
// zt[preR[k]+r, o] = sum_c zb[(k+2)*512 + r, c] * Wb[k, o, c]
// 128x128 tile, BK=32, 4 waves (2x2), 16x16x32 bf16 MFMA.
// grid = (240 row-tiles, 4 col-tiles)
// ---------------------------------------------------------------------------
__global__ __launch_bounds__(256) void gemm_bf16(const ushort* __restrict__ zb,
                                                 const ushort* __restrict__ Wb,
                                                 ushort* __restrict__ zt) {
  int rt = blockIdx.x, ct = blockIdx.y;
  int kk, Tk;
  if (rt < 56)       { kk = 0; Tk = 0;   }
  else if (rt < 108) { kk = 1; Tk = 56;  }
  else if (rt < 156) { kk = 2; Tk = 108; }
  else if (rt < 200) { kk = 3; Tk = 156; }
  else               { kk = 4; Tk = 200; }
  const int preR[5] = {0, 7168, 13824, 19968, 25600};
  int r0 = (rt - Tk) * 128;
  const ushort* A  = zb + ((size_t)(kk + 2) * 512 + r0) * 512;
  const ushort* Bw = Wb + (size_t)kk * 512 * 512 + (size_t)ct * 128 * 512;
  ushort* Cb = zt + ((size_t)preR[kk] + r0) * 512 + ct * 128;

  __shared__ __align__(16) ushort As[128][40];
  __shared__ __align__(16) ushort Bs[128][40];
  int tid = threadIdx.x;
  int wave = tid >> 6, lane = tid & 63;
  int wr = wave >> 1, wc = wave & 1;
  int lp = lane & 15, lg = lane >> 4;

  f32x4 acc[4][4];
#pragma unroll
  for (int m = 0; m < 4; ++m)
#pragma unroll
    for (int n = 0; n < 4; ++n) acc[m][n] = (f32x4){0.f, 0.f, 0.f, 0.f};

  for (int c0 = 0; c0 < 512; c0 += 32) {
#pragma unroll
    for (int it = 0; it < 2; ++it) {
      int f = tid + it * 256;
      int row = f >> 2, q = f & 3;
      uint4 va = *reinterpret_cast<const uint4*>(&A[(size_t)row * 512 + c0 + q * 8]);
      *reinterpret_cast<uint4*>(&As[row][q * 8]) = va;
      uint4 vb = *reinterpret_cast<const uint4*>(&Bw[(size_t)row * 512 + c0 + q * 8]);
      *reinterpret_cast<uint4*>(&Bs[row][q * 8]) = vb;
    }
    __syncthreads();
    bf16x8 af[4], bfr[4];
#pragma unroll
    for (int m = 0; m < 4; ++m)
      af[m] = *reinterpret_cast<const bf16x8*>(&As[wr * 64 + m * 16 + lp][lg * 8]);
#pragma unroll
    for (int n = 0; n < 4; ++n)
      bfr[n] = *reinterpret_cast<const bf16x8*>(&Bs[wc * 64 + n * 16 + lp][lg * 8]);
#pragma unroll
    for (int m = 0; m < 4; ++m)
#pragma unroll
      for (int n = 0; n < 4; ++n)
        acc[m][n] = __builtin_amdgcn_mfma_f32_16x16x32_bf16(af[m], bfr[n], acc[m][n], 0, 0, 0);
    __syncthreads();
  }
#pragma unroll
  for (int m = 0; m < 4; ++m)
#pragma unroll
    for (int n = 0; n < 4; ++n)
#pragma unroll
      for (int j = 0; j < 4; ++j) {
        int row = wr * 64 + m * 16 + lg * 4 + j;
        int col = wc * 64 + n * 16 + lp;
        Cb[(size_t)row * 512 + col] = f2bf(acc[m][n][j]);
      }
}

// ---------------------------------------------------------------------------
// Fused idx kernel: all 5 steps in one launch (491520 draws).
// ---------------------------------------------------------------------------
struct KeyParams {
  uint32_t k1a[5], k1b[5], k2a[5], k2b[5], mult[5];
};

__global__ __launch_bounds__(256) void idx_fused(int* __restrict__ idxb, KeyParams p) {
  int gid = blockIdx.x * 256 + threadIdx.x;
  int k; uint32_t span; int m;
  if (gid < 114688)      { k = 0; m = gid;          span = 7168; }
  else if (gid < 221184) { k = 1; m = gid - 114688; span = 6656; }
  else if (gid < 319488) { k = 2; m = gid - 221184; span = 6144; }
  else if (gid < 409600) { k = 3; m = gid - 319488; span = 5632; }
  else                   { k = 4; m = gid - 409600; span = 5120; }
  uint32_t h0, h1, l0, l1;
  tf2x32(p.k1a[k], p.k1b[k], 0u, (uint32_t)m, h0, h1);
  tf2x32(p.k2a[k], p.k2b[k], 0u, (uint32_t)m, l0, l1);
  uint32_t hi = h0 ^ h1, lo = l0 ^ l1;
  uint32_t off = ((hi % span) * p.mult[k] + (lo % span)) % span;
  idxb[gid] = (int)off;
}

// ---------------------------------------------------------------------------
// Fused loss: one wave per row (grid-strided over all 30720 rows).
// All rows bf16: 1 dwordx4 per lane per row. 17 independent gathers issued
// back-to-back for latency overlap. Per-block partial sum -> 1 atomic.
// ---------------------------------------------------------------------------
__device__ inline float wave_sum(float v) {
#pragma unroll
  for (int o = 32; o > 0; o >>= 1) v += __shfl_xor(v, o, 64);
  return v;
}

__device__ inline float dot8(uint4 v, const float* cx) {
  float a;
  a = __builtin_bit_cast(float, v.x << 16) * cx[0];
  a = fmaf(__builtin_bit_cast(float, v.x & 0xFFFF0000u), cx[1], a);
  a = fmaf(__builtin_bit_cast(float, v.y << 16),         cx[2], a);
  a = fmaf(__builtin_bit_cast(float, v.y & 0xFFFF0000u), cx[3], a);
  a = fmaf(__builtin_bit_cast(float, v.z << 16),         cx[4], a);
  a = fmaf(__builtin_bit_cast(float, v.z & 0xFFFF0000u), cx[5], a);
  a = fmaf(__builtin_bit_cast(float, v.w << 16),         cx[6], a);
  a = fmaf(__builtin_bit_cast(float, v.w & 0xFFFF0000u), cx[7], a);
  return a;
}

__global__ __launch_bounds__(256) void loss_fused(const ushort* __restrict__ zt,
                                                  const ushort* __restrict__ cb,
                                                  const int* __restrict__ idxb,
                                                  float* __restrict__ out) {
  int tid = threadIdx.x;
  int wave = tid >> 6, lane = tid & 63;
  int wg = blockIdx.x * 4 + wave;  // 0..8191
  float lsum = 0.f;
  for (int g_r = wg; g_r < 30720; g_r += 8192) {
    int base; float scale;
    if (g_r < 7168)       { base = 0;     scale = 1.f / (7168.f * 5.f); }
    else if (g_r < 13824) { base = 7168;  scale = 1.f / (6656.f * 5.f); }
    else if (g_r < 19968) { base = 13824; scale = 1.f / (6144.f * 5.f); }
    else if (g_r < 25600) { base = 19968; scale = 1.f / (5632.f * 5.f); }
    else                  { base = 25600; scale = 1.f / (5120.f * 5.f); }
    int rloc = g_r - base;

    uint4 cv = *reinterpret_cast<const uint4*>(&cb[(size_t)rloc * 512 + lane * 8]);
    uint4 pv = *reinterpret_cast<const uint4*>(&zt[(size_t)g_r * 512 + lane * 8]);
    const int4* ip = reinterpret_cast<const int4*>(&idxb[(size_t)g_r * 16]);
    int4 i0 = ip[0], i1 = ip[1], i2 = ip[2], i3 = ip[3];
    int rn[16] = {i0.x, i0.y, i0.z, i0.w, i1.x, i1.y, i1.z, i1.w,
                  i2.x, i2.y, i2.z, i2.w, i3.x, i3.y, i3.z, i3.w};

    float cx[8];
    cx[0] = __builtin_bit_cast(float, cv.x << 16);
    cx[1] = __builtin_bit_cast(float, cv.x & 0xFFFF0000u);
    cx[2] = __builtin_bit_cast(float, cv.y << 16);
    cx[3] = __builtin_bit_cast(float, cv.y & 0xFFFF0000u);
    cx[4] = __builtin_bit_cast(float, cv.z << 16);
    cx[5] = __builtin_bit_cast(float, cv.z & 0xFFFF0000u);
    cx[6] = __builtin_bit_cast(float, cv.w << 16);
    cx[7] = __builtin_bit_cast(float, cv.w & 0xFFFF0000u);

    float s[17];
    s[0] = dot8(pv, cx);
#pragma unroll
    for (int n = 0; n < 16; ++n) {
      uint4 nv = *reinterpret_cast<const uint4*>(
          &zt[((size_t)(base + rn[n])) * 512 + lane * 8]);
      s[1 + n] = dot8(nv, cx);
    }
#pragma unroll
    for (int i = 0; i < 17; ++i) s[i] = wave_sum(s[i]);
    float mx = s[0];
#pragma unroll
    for (int i = 1; i < 17; ++i) mx = fmaxf(mx, s[i]);
    float se = 0.f;
#pragma unroll
    for (int i = 0; i < 17; ++i) se += __expf(s[i] - mx);
    float p0 = __expf(s[0] - mx) / se;
    lsum += -logf(p0 + 1e-11f) * scale;
  }
  __shared__ float red[4];
  if (lane == 0) red[wave] = lsum;
  __syncthreads();
  if (tid == 0) atomicAdd(out, red[0] + red[1] + red[2] + red[3]);
}

__global__ void zero_out(float* o) {
  if (threadIdx.x == 0) o[0] = 0.0f;
}

// ---------------------------------------------------------------------------
extern "C" void kernel_launch(void* const* d_in, const int* in_sizes, int n_in,
                              void* d_out, int out_size, void* d_ws, size_t ws_size,
                              hipStream_t stream) {
  const float* z = (const float*)d_in[0];
  const float* c = (const float*)d_in[1];
  const float* W = (const float*)d_in[2];
  float* out = (float*)d_out;

  // workspace layout (bf16 = ushort)
  ushort* zb = (ushort*)d_ws;              // 8192*512        = 8 MB
  ushort* cb = zb + (size_t)8192 * 512;    // 8192*512        = 8 MB
  ushort* Wb = cb + (size_t)8192 * 512;    // 5*512*512       = 2.6 MB
  ushort* zt = Wb + (size_t)1310720;       // 30720*512       = 31.5 MB
  int* idxb  = (int*)(zt + (size_t)15728640);  // 491520 ints = 2 MB

  zero_out<<<dim3(1), dim3(64), 0, stream>>>(out);
  perm_bf16<<<dim3(512), dim3(256), 0, stream>>>(z, zb);
  perm_bf16<<<dim3(512), dim3(256), 0, stream>>>(c, cb);
  conv_w<<<dim3(1280), dim3(256), 0, stream>>>((const float4*)W, Wb);

  gemm_bf16<<<dim3(240, 4), dim3(256), 0, stream>>>(zb, Wb, zt);

  KeyParams p;
  for (int k = 1; k <= 5; ++k) {
    int Gp = 16 - (k + 1);
    uint32_t span = (uint32_t)(Gp * 512);
    p.mult[k - 1] = (uint32_t)((1ull << 32) % (uint64_t)span);
    uint32_t key0 = 0u, key1 = (uint32_t)(1000 + k);
    tf2x32(key0, key1, 0u, 0u, p.k1a[k - 1], p.k1b[k - 1]);
    tf2x32(key0, key1, 0u, 1u, p.k2a[k - 1], p.k2b[k - 1]);
  }
  idx_fused<<<dim3(1920), dim3(256), 0, stream>>>(idxb, p);

  loss_fused<<<dim3(2048), dim3(256), 0, stream>>>(zt, cb, idxb, out);
}

// Round 4
// 181.907 us; speedup vs baseline: 4.6869x; 1.1222x over previous
//
#include <hip/hip_runtime.h>
#include <stdint.h>

// ---------------------------------------------------------------------------
// InfoNCE loss (B=32, C=512, G=16, P=5, neg=16, skip=1), fp32 inputs.
// Round 4: fused prep (perm+convW+idx+zero), m97-style global_load_lds MFMA
// GEMM, 16-lane-per-row loss gather (4 rows/wave, exact work balance).
// Threefry partitionable verified bit-exact (rounds 2-3, absmax 0.0).
// ---------------------------------------------------------------------------

typedef __attribute__((ext_vector_type(8))) short bf16x8;
typedef __attribute__((ext_vector_type(4))) float f32x4;

using gld_gp = const __attribute__((address_space(1))) uint32_t*;
using gld_lp = __attribute__((address_space(3))) uint32_t*;

__host__ __device__ inline uint32_t rotl32(uint32_t x, int d) {
  return (x << d) | (x >> (32 - d));
}

__host__ __device__ inline void tf2x32(uint32_t k0, uint32_t k1,
                                       uint32_t x0, uint32_t x1,
                                       uint32_t& o0, uint32_t& o1) {
  uint32_t ks0 = k0, ks1 = k1, ks2 = 0x1BD11BDAu ^ k0 ^ k1;
  x0 += ks0; x1 += ks1;
#define TF_R(r) { x0 += x1; x1 = rotl32(x1, (r)); x1 ^= x0; }
  TF_R(13) TF_R(15) TF_R(26) TF_R(6)
  x0 += ks1; x1 += ks2 + 1u;
  TF_R(17) TF_R(29) TF_R(16) TF_R(24)
  x0 += ks2; x1 += ks0 + 2u;
  TF_R(13) TF_R(15) TF_R(26) TF_R(6)
  x0 += ks0; x1 += ks1 + 3u;
  TF_R(17) TF_R(29) TF_R(16) TF_R(24)
  x0 += ks1; x1 += ks2 + 4u;
  TF_R(13) TF_R(15) TF_R(26) TF_R(6)
  x0 += ks2; x1 += ks0 + 5u;
#undef TF_R
  o0 = x0; o1 = x1;
}

__device__ inline ushort f2bf(float f) {
  uint32_t u = __builtin_bit_cast(uint32_t, f);
  u += 0x7FFFu + ((u >> 16) & 1u);
  return (ushort)(u >> 16);
}

struct KeyParams {
  uint32_t k1a[5], k1b[5], k2a[5], k2b[5], mult[5];
};

// ---------------------------------------------------------------------------
// Fused prep kernel:
//  blocks [0,512)     : perm z -> zb (bf16)
//  blocks [512,1024)  : perm c -> cb (bf16)
//  blocks [1024,2304) : W fp32 -> bf16
//  blocks [2304,4224) : threefry idx (+ zero out on first)
// ---------------------------------------------------------------------------
__global__ __launch_bounds__(256) void prep_kernel(const float* __restrict__ z,
                                                   const float* __restrict__ c,
                                                   const float4* __restrict__ W,
                                                   ushort* __restrict__ zb,
                                                   ushort* __restrict__ cb,
                                                   ushort* __restrict__ Wb,
                                                   int* __restrict__ idxb,
                                                   float* __restrict__ out,
                                                   KeyParams p) {
  int blk = blockIdx.x;
  int t = threadIdx.x;
  if (blk < 1024) {
    // permute: dst[((g*16+j)*32+b)*512+cc] = bf16(src[b*131072+cc*256+g*16+j])
    const float* src = (blk < 512) ? z : c;
    ushort* dst = (blk < 512) ? zb : cb;
    int bb = blk & 511;
    int g = bb >> 5, b = bb & 31;
    __shared__ ushort tile[512][17];
#pragma unroll 4
    for (int it = 0; it < 32; ++it) {
      int e = it * 256 + t;
      int cc = e >> 4, j = e & 15;
      tile[cc][j] = f2bf(src[b * 131072 + cc * 256 + g * 16 + j]);
    }
    __syncthreads();
#pragma unroll 4
    for (int it = 0; it < 32; ++it) {
      int e = it * 256 + t;
      int cc = e & 511, jj = e >> 9;
      dst[(size_t)((g * 16 + jj) * 32 + b) * 512 + cc] = tile[cc][jj];
    }
  } else if (blk < 2304) {
    int gid = (blk - 1024) * 256 + t;
    if (gid < 327680) {
      float4 v = W[gid];
      ushort4 o;
      o.x = f2bf(v.x); o.y = f2bf(v.y); o.z = f2bf(v.z); o.w = f2bf(v.w);
      *reinterpret_cast<ushort4*>(&Wb[(size_t)gid * 4]) = o;
    }
  } else {
    int gid = (blk - 2304) * 256 + t;
    if (gid == 0) out[0] = 0.0f;
    int k; uint32_t span; int m;
    if (gid < 114688)      { k = 0; m = gid;          span = 7168; }
    else if (gid < 221184) { k = 1; m = gid - 114688; span = 6656; }
    else if (gid < 319488) { k = 2; m = gid - 221184; span = 6144; }
    else if (gid < 409600) { k = 3; m = gid - 319488; span = 5632; }
    else                   { k = 4; m = gid - 409600; span = 5120; }
    uint32_t h0, h1, l0, l1;
    tf2x32(p.k1a[k], p.k1b[k], 0u, (uint32_t)m, h0, h1);
    tf2x32(p.k2a[k], p.k2b[k], 0u, (uint32_t)m, l0, l1);
    uint32_t hi = h0 ^ h1, lo = l0 ^ l1;
    uint32_t off = ((hi % span) * p.mult[k] + (lo % span)) % span;
    idxb[gid] = (int)off;
  }
}

// ---------------------------------------------------------------------------
// Batched bf16 MFMA GEMM, m97 structure: global_load_lds (16B) into linear
// LDS [128][32], 128x128 tile, BK=32, 4 waves (2x2), 16x16x32 bf16 MFMA.
// ---------------------------------------------------------------------------
__global__ __launch_bounds__(256) void gemm_bf16(const ushort* __restrict__ zb,
                                                 const ushort* __restrict__ Wb,
                                                 ushort* __restrict__ zt) {
  int rt = blockIdx.x, ct = blockIdx.y;
  int kk, Tk;
  if (rt < 56)       { kk = 0; Tk = 0;   }
  else if (rt < 108) { kk = 1; Tk = 56;  }
  else if (rt < 156) { kk = 2; Tk = 108; }
  else if (rt < 200) { kk = 3; Tk = 156; }
  else               { kk = 4; Tk = 200; }
  const int preR[5] = {0, 7168, 13824, 19968, 25600};
  int r0 = (rt - Tk) * 128;
  const ushort* A  = zb + ((size_t)(kk + 2) * 512 + r0) * 512;
  const ushort* Bw = Wb + (size_t)kk * 512 * 512 + (size_t)ct * 128 * 512;
  ushort* Cb = zt + ((size_t)preR[kk] + r0) * 512 + ct * 128;

  __shared__ __align__(1024) ushort As[4096];  // [128][32] linear
  __shared__ __align__(1024) ushort Bs[4096];
  int tid = threadIdx.x;
  int wave = tid >> 6, lane = tid & 63;
  int wr = wave >> 1, wc = wave & 1;
  int lp = lane & 15, lg = lane >> 4;

  f32x4 acc[4][4];
#pragma unroll
  for (int m = 0; m < 4; ++m)
#pragma unroll
    for (int n = 0; n < 4; ++n) acc[m][n] = (f32x4){0.f, 0.f, 0.f, 0.f};

  int lrow = lane >> 2, lq = lane & 3;  // lane's row/quad within a 1KB chunk
  for (int c0 = 0; c0 < 512; c0 += 32) {
#pragma unroll
    for (int it = 0; it < 2; ++it) {
      int chunk = wave * 2 + it;            // 0..7, each 1024B = 16 rows
      int row = chunk * 16 + lrow;
      __builtin_amdgcn_global_load_lds(
          (gld_gp)(const void*)(A + (size_t)row * 512 + c0 + lq * 8),
          (gld_lp)(void*)(As + chunk * 512 + lane * 8), 16, 0, 0);
      __builtin_amdgcn_global_load_lds(
          (gld_gp)(const void*)(Bw + (size_t)row * 512 + c0 + lq * 8),
          (gld_lp)(void*)(Bs + chunk * 512 + lane * 8), 16, 0, 0);
    }
    __syncthreads();
    bf16x8 af[4], bfr[4];
#pragma unroll
    for (int m = 0; m < 4; ++m)
      af[m] = *reinterpret_cast<const bf16x8*>(&As[(wr * 64 + m * 16 + lp) * 32 + lg * 8]);
#pragma unroll
    for (int n = 0; n < 4; ++n)
      bfr[n] = *reinterpret_cast<const bf16x8*>(&Bs[(wc * 64 + n * 16 + lp) * 32 + lg * 8]);
#pragma unroll
    for (int m = 0; m < 4; ++m)
#pragma unroll
      for (int n = 0; n < 4; ++n)
        acc[m][n] = __builtin_amdgcn_mfma_f32_16x16x32_bf16(af[m], bfr[n], acc[m][n], 0, 0, 0);
    __syncthreads();
  }
#pragma unroll
  for (int m = 0; m < 4; ++m)
#pragma unroll
    for (int n = 0; n < 4; ++n)
#pragma unroll
      for (int j = 0; j < 4; ++j) {
        int row = wr * 64 + m * 16 + lg * 4 + j;
        int col = wc * 64 + n * 16 + lp;
        Cb[(size_t)row * 512 + col] = f2bf(acc[m][n][j]);
      }
}

// ---------------------------------------------------------------------------
// Loss: 16 lanes per row, 4 rows per wave, 960 blocks x 2 passes (exact).
// Per lane: 32 channels (4x dwordx4 per row). 4-step shfl reduce within 16.
// ---------------------------------------------------------------------------
__device__ inline float bflo(uint32_t u) { return __builtin_bit_cast(float, u << 16); }
__device__ inline float bfhi(uint32_t u) { return __builtin_bit_cast(float, u & 0xFFFF0000u); }

__device__ inline float dot8v(uint4 v, const float* cx) {
  float a = bflo(v.x) * cx[0];
  a = fmaf(bfhi(v.x), cx[1], a);
  a = fmaf(bflo(v.y), cx[2], a);
  a = fmaf(bfhi(v.y), cx[3], a);
  a = fmaf(bflo(v.z), cx[4], a);
  a = fmaf(bfhi(v.z), cx[5], a);
  a = fmaf(bflo(v.w), cx[6], a);
  a = fmaf(bfhi(v.w), cx[7], a);
  return a;
}

__device__ inline float dot32(const uint4* p, const float* cx) {
  uint4 a = p[0], b = p[1], c = p[2], d = p[3];
  return dot8v(a, cx) + dot8v(b, cx + 8) + dot8v(c, cx + 16) + dot8v(d, cx + 24);
}

__global__ __launch_bounds__(256) void loss_fused(const ushort* __restrict__ zt,
                                                  const ushort* __restrict__ cb,
                                                  const int* __restrict__ idxb,
                                                  float* __restrict__ out) {
  int tid = threadIdx.x;
  int wave = tid >> 6, lane = tid & 63;
  int g = lane >> 4, lp = lane & 15;
  float lsum = 0.f;
#pragma unroll
  for (int pass = 0; pass < 2; ++pass) {
    int r = pass * 15360 + blockIdx.x * 16 + wave * 4 + g;
    int base; float scale;
    if (r < 7168)       { base = 0;     scale = 1.f / (7168.f * 5.f); }
    else if (r < 13824) { base = 7168;  scale = 1.f / (6656.f * 5.f); }
    else if (r < 19968) { base = 13824; scale = 1.f / (6144.f * 5.f); }
    else if (r < 25600) { base = 19968; scale = 1.f / (5632.f * 5.f); }
    else                { base = 25600; scale = 1.f / (5120.f * 5.f); }
    int rloc = r - base;

    // context row: 32 channels per lane
    float cx[32];
    {
      const uint4* c4 = reinterpret_cast<const uint4*>(&cb[(size_t)rloc * 512 + lp * 32]);
      uint4 v0 = c4[0], v1 = c4[1], v2 = c4[2], v3 = c4[3];
      uint4 vv[4] = {v0, v1, v2, v3};
#pragma unroll
      for (int q = 0; q < 4; ++q) {
        cx[q * 8 + 0] = bflo(vv[q].x); cx[q * 8 + 1] = bfhi(vv[q].x);
        cx[q * 8 + 2] = bflo(vv[q].y); cx[q * 8 + 3] = bfhi(vv[q].y);
        cx[q * 8 + 4] = bflo(vv[q].z); cx[q * 8 + 5] = bfhi(vv[q].z);
        cx[q * 8 + 6] = bflo(vv[q].w); cx[q * 8 + 7] = bfhi(vv[q].w);
      }
    }
    const int4* ip = reinterpret_cast<const int4*>(&idxb[(size_t)r * 16]);
    int4 i0 = ip[0], i1 = ip[1], i2 = ip[2], i3 = ip[3];
    int rn[16] = {i0.x, i0.y, i0.z, i0.w, i1.x, i1.y, i1.z, i1.w,
                  i2.x, i2.y, i2.z, i2.w, i3.x, i3.y, i3.z, i3.w};

    float s[17];
    s[0] = dot32(reinterpret_cast<const uint4*>(&zt[(size_t)r * 512 + lp * 32]), cx);
#pragma unroll
    for (int n = 0; n < 16; ++n) {
      s[1 + n] = dot32(reinterpret_cast<const uint4*>(
                     &zt[(size_t)(base + rn[n]) * 512 + lp * 32]), cx);
    }
#pragma unroll
    for (int i = 0; i < 17; ++i) {
#pragma unroll
      for (int o = 8; o > 0; o >>= 1) s[i] += __shfl_xor(s[i], o, 64);
    }
    float mx = s[0];
#pragma unroll
    for (int i = 1; i < 17; ++i) mx = fmaxf(mx, s[i]);
    float se = 0.f;
#pragma unroll
    for (int i = 0; i < 17; ++i) se += __expf(s[i] - mx);
    float p0 = __expf(s[0] - mx) / se;
    if (lp == 0) lsum += -logf(p0 + 1e-11f) * scale;
  }
  __shared__ float red[16];
  if (lp == 0) red[wave * 4 + g] = lsum;
  __syncthreads();
  if (tid == 0) {
    float tsum = 0.f;
#pragma unroll
    for (int i = 0; i < 16; ++i) tsum += red[i];
    atomicAdd(out, tsum);
  }
}

// ---------------------------------------------------------------------------
extern "C" void kernel_launch(void* const* d_in, const int* in_sizes, int n_in,
                              void* d_out, int out_size, void* d_ws, size_t ws_size,
                              hipStream_t stream) {
  const float* z = (const float*)d_in[0];
  const float* c = (const float*)d_in[1];
  const float* W = (const float*)d_in[2];
  float* out = (float*)d_out;

  ushort* zb = (ushort*)d_ws;                 // 8192*512 bf16 = 8 MB
  ushort* cb = zb + (size_t)8192 * 512;       // 8 MB
  ushort* Wb = cb + (size_t)8192 * 512;       // 5*512*512 = 2.6 MB
  ushort* zt = Wb + (size_t)1310720;          // 30720*512 = 31.5 MB
  int* idxb  = (int*)(zt + (size_t)15728640); // 491520 ints = 2 MB

  KeyParams p;
  for (int k = 1; k <= 5; ++k) {
    int Gp = 16 - (k + 1);
    uint32_t span = (uint32_t)(Gp * 512);
    p.mult[k - 1] = (uint32_t)((1ull << 32) % (uint64_t)span);
    uint32_t key0 = 0u, key1 = (uint32_t)(1000 + k);
    tf2x32(key0, key1, 0u, 0u, p.k1a[k - 1], p.k1b[k - 1]);
    tf2x32(key0, key1, 0u, 1u, p.k2a[k - 1], p.k2b[k - 1]);
  }

  prep_kernel<<<dim3(4224), dim3(256), 0, stream>>>(z, c, (const float4*)W,
                                                    zb, cb, Wb, idxb, out, p);
  gemm_bf16<<<dim3(240, 4), dim3(256), 0, stream>>>(zb, Wb, zt);
  loss_fused<<<dim3(960), dim3(256), 0, stream>>>(zt, cb, idxb, out);
}